// Round 4
// baseline (502.137 us; speedup 1.0000x reference)
//
#include <hip/hip_runtime.h>
#include <hip/hip_bf16.h>
#include <hip/hip_fp16.h>

#define N_NODES 100000
#define D 256
#define R_REL 8
#define E_EDGES 40000
#define B_BASES 4
#define LN_EPS 1e-5f
#define RN (R_REL * N_NODES)          // 800000
#define SCAN_CH 1024
#define SCAN_NB ((RN + SCAN_CH - 1) / SCAN_CH)   // 782

typedef __attribute__((ext_vector_type(8))) short short8;
typedef __attribute__((ext_vector_type(4))) float f32x4;

__device__ inline short bf16_of(float f) {
    __hip_bfloat16 h = __float2bfloat16(f);
    return *reinterpret_cast<short*>(&h);
}

// ---------------------------------------------------------------------------
// Wt[r][o][d] = sum_b coeff[r,b] * bases[b][d][o]   (bf16, transposed)
__global__ __launch_bounds__(256) void k_prepW(const float* __restrict__ bases,
                                               const float* __restrict__ coeff,
                                               ushort* __restrict__ Wt) {
    __shared__ float tile[64][65];
    int r  = blockIdx.x >> 4;
    int dt = (blockIdx.x >> 2) & 3, ot = blockIdx.x & 3;
    int t = threadIdx.x;
    float c0 = coeff[r * 4 + 0], c1 = coeff[r * 4 + 1];
    float c2 = coeff[r * 4 + 2], c3 = coeff[r * 4 + 3];
    int cl = t & 63, rw = t >> 6;
    for (int i = 0; i < 16; ++i) {
        int dl = i * 4 + rw;
        size_t gi = (size_t)(dt * 64 + dl) * D + ot * 64 + cl;
        tile[dl][cl] = c0 * bases[gi] + c1 * bases[65536 + gi]
                     + c2 * bases[2 * 65536 + gi] + c3 * bases[3 * 65536 + gi];
    }
    __syncthreads();
    for (int i = 0; i < 16; ++i) {
        int ol = i * 4 + rw;
        Wt[(size_t)r * 65536 + (size_t)(ot * 64 + ol) * D + dt * 64 + cl] =
            (ushort)bf16_of(tile[cl][ol]);
    }
}

// wt_self[o][d] = bf16(w_self[d][o])
__global__ __launch_bounds__(256) void k_wselfT(const float* __restrict__ w,
                                                ushort* __restrict__ Wt) {
    __shared__ float tile[64][65];
    int dt = blockIdx.x >> 2, ot = blockIdx.x & 3;
    int t = threadIdx.x;
    int cl = t & 63, rw = t >> 6;
    for (int i = 0; i < 16; ++i) {
        int dl = i * 4 + rw;
        tile[dl][cl] = w[(size_t)(dt * 64 + dl) * D + ot * 64 + cl];
    }
    __syncthreads();
    for (int i = 0; i < 16; ++i) {
        int ol = i * 4 + rw;
        Wt[(size_t)(ot * 64 + ol) * D + dt * 64 + cl] = (ushort)bf16_of(tile[cl][ol]);
    }
}

// ---------------------------------------------------------------------------
// CSR build: histogram -> exclusive scan -> scatter src ids
__global__ void k_count(const int* __restrict__ ei, int* __restrict__ deg) {
    int idx = blockIdx.x * blockDim.x + threadIdx.x;
    if (idx >= R_REL * E_EDGES) return;
    int r = idx / E_EDGES, e = idx % E_EDGES;
    int dst = ei[(r * 2 + 1) * E_EDGES + e];
    atomicAdd(&deg[r * N_NODES + dst], 1);
}

__global__ __launch_bounds__(256) void k_scanA(const int* __restrict__ deg,
                                               int* __restrict__ start,
                                               int* __restrict__ sumsA) {
    __shared__ int sc[256];
    int t = threadIdx.x;
    int base = blockIdx.x * SCAN_CH + t * 4;
    int v0 = (base + 0 < RN) ? deg[base + 0] : 0;
    int v1 = (base + 1 < RN) ? deg[base + 1] : 0;
    int v2 = (base + 2 < RN) ? deg[base + 2] : 0;
    int v3 = (base + 3 < RN) ? deg[base + 3] : 0;
    int ts = v0 + v1 + v2 + v3;
    sc[t] = ts;
    __syncthreads();
    for (int off = 1; off < 256; off <<= 1) {
        int val = (t >= off) ? sc[t - off] : 0;
        __syncthreads();
        sc[t] += val;
        __syncthreads();
    }
    int excl = sc[t] - ts;
    if (base + 0 < RN) start[base + 0] = excl;
    if (base + 1 < RN) start[base + 1] = excl + v0;
    if (base + 2 < RN) start[base + 2] = excl + v0 + v1;
    if (base + 3 < RN) start[base + 3] = excl + v0 + v1 + v2;
    if (t == 255) sumsA[blockIdx.x] = sc[255];
}

__global__ __launch_bounds__(256) void k_scanB(const int* __restrict__ sumsA,
                                               int* __restrict__ sumsB) {
    __shared__ int sc[256];
    int t = threadIdx.x;
    int i0 = t * 4;
    int v0 = (i0 + 0 < SCAN_NB) ? sumsA[i0 + 0] : 0;
    int v1 = (i0 + 1 < SCAN_NB) ? sumsA[i0 + 1] : 0;
    int v2 = (i0 + 2 < SCAN_NB) ? sumsA[i0 + 2] : 0;
    int v3 = (i0 + 3 < SCAN_NB) ? sumsA[i0 + 3] : 0;
    int ts = v0 + v1 + v2 + v3;
    sc[t] = ts;
    __syncthreads();
    for (int off = 1; off < 256; off <<= 1) {
        int val = (t >= off) ? sc[t - off] : 0;
        __syncthreads();
        sc[t] += val;
        __syncthreads();
    }
    int excl = sc[t] - ts;
    if (i0 + 0 < SCAN_NB) sumsB[i0 + 0] = excl;
    if (i0 + 1 < SCAN_NB) sumsB[i0 + 1] = excl + v0;
    if (i0 + 2 < SCAN_NB) sumsB[i0 + 2] = excl + v0 + v1;
    if (i0 + 3 < SCAN_NB) sumsB[i0 + 3] = excl + v0 + v1 + v2;
}

__global__ __launch_bounds__(256) void k_scanC(int* __restrict__ start,
                                               const int* __restrict__ sumsB,
                                               int* __restrict__ cursor) {
    int idx = blockIdx.x * blockDim.x + threadIdx.x;
    if (idx < RN) {
        int v = start[idx] + sumsB[idx / SCAN_CH];
        start[idx] = v;
        cursor[idx] = v;
    }
    if (idx == 0) start[RN] = R_REL * E_EDGES;
}

__global__ void k_scatter(const int* __restrict__ ei, int* __restrict__ cursor,
                          int* __restrict__ sorted_src) {
    int idx = blockIdx.x * blockDim.x + threadIdx.x;
    if (idx >= R_REL * E_EDGES) return;
    int r = idx / E_EDGES, e = idx % E_EDGES;
    int src = ei[r * 2 * E_EDGES + e];
    int dst = ei[(r * 2 + 1) * E_EDGES + e];
    int pos = atomicAdd(&cursor[r * N_NODES + dst], 1);
    sorted_src[pos] = src;
}

// ---------------------------------------------------------------------------
__device__ inline void stage_row(short8* xs, const float* __restrict__ src_row,
                                 int rr, int c) {
    const float4* xp = (const float4*)(src_row + c * 8);
    float4 f0 = xp[0], f1 = xp[1];
    short8 v;
    v[0] = bf16_of(f0.x); v[1] = bf16_of(f0.y); v[2] = bf16_of(f0.z); v[3] = bf16_of(f0.w);
    v[4] = bf16_of(f1.x); v[5] = bf16_of(f1.y); v[6] = bf16_of(f1.z); v[7] = bf16_of(f1.w);
    xs[rr * 32 + (c ^ (rr & 7))] = v;
}

__device__ inline void gemm_tile(const short8* xs, const ushort* __restrict__ Wg,
                                 int lr, int lg, int w, f32x4 acc[4][4]) {
    for (int kk = 0; kk < 8; ++kk) {
        short8 a[4], b[4];
#pragma unroll
        for (int mi = 0; mi < 4; ++mi) {
            int row = mi * 16 + lr;
            int ch = kk * 4 + lg;
            a[mi] = xs[row * 32 + (ch ^ (row & 7))];
        }
#pragma unroll
        for (int ni = 0; ni < 4; ++ni) {
            int col = w * 64 + ni * 16 + lr;
            b[ni] = *reinterpret_cast<const short8*>(Wg + (size_t)col * D + kk * 32 + lg * 8);
        }
#pragma unroll
        for (int mi = 0; mi < 4; ++mi)
#pragma unroll
            for (int ni = 0; ni < 4; ++ni)
                acc[mi][ni] = __builtin_amdgcn_mfma_f32_16x16x32_bf16(
                    a[mi], b[ni], acc[mi][ni], 0, 0, 0);
    }
}

// ---------------------------------------------------------------------------
// Fully fused: out = LN(SiLU(x@Ws + b + sum_r (invdeg_r * segsum_r(x)) @ W_r))
__global__ __launch_bounds__(256) void k_fused(const float* __restrict__ x,
                                               const int* __restrict__ sorted_src,
                                               const int* __restrict__ start,
                                               const ushort* __restrict__ Wt,
                                               const ushort* __restrict__ WtS,
                                               const float* __restrict__ bias,
                                               const float* __restrict__ gamma,
                                               const float* __restrict__ beta,
                                               float* __restrict__ out) {
    __shared__ short8 xs[64 * 32];          // 32 KB A-tile
    __shared__ float red[2][64][4];
    int t = threadIdx.x;
    int n0 = blockIdx.x * 64;
    int nend = min(n0 + 64, N_NODES);
    int l = t & 63, w = t >> 6;
    int lr = l & 15, lg = l >> 4;
    int c = t & 31, g = t >> 5;             // staging: 8 groups of 32 lanes

    // ---- self phase: stage x rows, GEMM vs WtS
    for (int i = 0; i < 8; ++i) {
        int rr = i * 8 + g;
        int src = min(n0 + rr, N_NODES - 1);
        stage_row(xs, x + (size_t)src * D, rr, c);
    }
    __syncthreads();
    f32x4 acc[4][4] = {};
    gemm_tile(xs, WtS, lr, lg, w, acc);

    // ---- edge phases: z = invdeg * segment-sum of x rows, GEMM vs W_r
    for (int r = 0; r < R_REL; ++r) {
        const int* st = start + r * N_NODES;
        // skip relation if this block has no edges at all (rare)
        if (st[n0] == start[r * N_NODES + nend]) continue;
        __syncthreads();                     // xs free (prior GEMM done)
        for (int i = 0; i < 8; ++i) {
            int rl = i * 8 + g;
            int n = n0 + rl;
            float z[8] = {0.f, 0.f, 0.f, 0.f, 0.f, 0.f, 0.f, 0.f};
            int s = 0, e2 = 0;
            if (n < N_NODES) { s = st[n]; e2 = st[n + 1]; }
            float inv = 1.0f / fmaxf((float)(e2 - s), 1.0f);
            for (int p = s; p < e2; ++p) {
                int src = sorted_src[p];
                const float4* xp = (const float4*)(x + (size_t)src * D + c * 8);
                float4 f0 = xp[0], f1 = xp[1];
                z[0] += f0.x; z[1] += f0.y; z[2] += f0.z; z[3] += f0.w;
                z[4] += f1.x; z[5] += f1.y; z[6] += f1.z; z[7] += f1.w;
            }
            short8 v;
#pragma unroll
            for (int k2 = 0; k2 < 8; ++k2) v[k2] = bf16_of(z[k2] * inv);
            xs[rl * 32 + (c ^ (rl & 7))] = v;
        }
        __syncthreads();
        gemm_tile(xs, Wt + (size_t)r * 65536, lr, lg, w, acc);
    }

    // ---- bias + SiLU + LN partials
    int colbase = w * 64;
    float bv[4];
#pragma unroll
    for (int ni = 0; ni < 4; ++ni) bv[ni] = bias[colbase + ni * 16 + lr];
#pragma unroll
    for (int mi = 0; mi < 4; ++mi) {
#pragma unroll
        for (int j = 0; j < 4; ++j) {
            float s = 0.f, q = 0.f;
#pragma unroll
            for (int ni = 0; ni < 4; ++ni) {
                float va = acc[mi][ni][j] + bv[ni];
                float aa = va / (1.f + expf(-va));
                acc[mi][ni][j] = aa;
                s += aa; q += aa * aa;
            }
#pragma unroll
            for (int off = 1; off < 16; off <<= 1) {
                s += __shfl_xor(s, off, 64);
                q += __shfl_xor(q, off, 64);
            }
            if (lr == 0) {
                int rl = mi * 16 + lg * 4 + j;
                red[0][rl][w] = s; red[1][rl][w] = q;
            }
        }
    }
    __syncthreads();
    float gv[4], bt[4];
#pragma unroll
    for (int ni = 0; ni < 4; ++ni) {
        gv[ni] = gamma[colbase + ni * 16 + lr];
        bt[ni] = beta[colbase + ni * 16 + lr];
    }
#pragma unroll
    for (int mi = 0; mi < 4; ++mi) {
#pragma unroll
        for (int j = 0; j < 4; ++j) {
            int rl = mi * 16 + lg * 4 + j;
            int rg = n0 + rl;
            if (rg >= N_NODES) continue;
            float s = red[0][rl][0] + red[0][rl][1] + red[0][rl][2] + red[0][rl][3];
            float q = red[1][rl][0] + red[1][rl][1] + red[1][rl][2] + red[1][rl][3];
            float mean = s * (1.0f / 256.0f);
            float var = q * (1.0f / 256.0f) - mean * mean;
            float rs = rsqrtf(var + LN_EPS);
            float* op = out + (size_t)rg * D + colbase + lr;
#pragma unroll
            for (int ni = 0; ni < 4; ++ni)
                op[ni * 16] = (acc[mi][ni][j] - mean) * rs * gv[ni] + bt[ni];
        }
    }
}

// ---------------------------------------------------------------------------
extern "C" void kernel_launch(void* const* d_in, const int* in_sizes, int n_in,
                              void* d_out, int out_size, void* d_ws, size_t ws_size,
                              hipStream_t stream) {
    const float* x      = (const float*)d_in[0];
    const int*   ei     = (const int*)d_in[1];
    const float* bases  = (const float*)d_in[2];
    const float* coeff  = (const float*)d_in[3];
    const float* w_self = (const float*)d_in[4];
    const float* b_self = (const float*)d_in[5];
    const float* gamma  = (const float*)d_in[6];
    const float* beta   = (const float*)d_in[7];
    float* out = (float*)d_out;

    ushort* Wt  = (ushort*)d_ws;                     // R*D*D bf16
    ushort* WtS = Wt + (size_t)R_REL * D * D;        // D*D bf16
    int* deg    = (int*)(WtS + (size_t)D * D);       // RN
    int* start  = deg + RN;                          // RN+1
    int* cursor = start + RN + 1;                    // RN
    int* sumsA  = cursor + RN;                       // SCAN_NB (<800)
    int* sumsB  = sumsA + 800;                       // SCAN_NB
    int* sorted_src = sumsB + 800;                   // R*E

    hipMemsetAsync(deg, 0, (size_t)RN * sizeof(int), stream);

    k_prepW<<<R_REL * 16, 256, 0, stream>>>(bases, coeff, Wt);
    k_wselfT<<<16, 256, 0, stream>>>(w_self, WtS);
    k_count<<<(R_REL * E_EDGES + 255) / 256, 256, 0, stream>>>(ei, deg);
    k_scanA<<<SCAN_NB, 256, 0, stream>>>(deg, start, sumsA);
    k_scanB<<<1, 256, 0, stream>>>(sumsA, sumsB);
    k_scanC<<<(RN + 255) / 256, 256, 0, stream>>>(start, sumsB, cursor);
    k_scatter<<<(R_REL * E_EDGES + 255) / 256, 256, 0, stream>>>(ei, cursor, sorted_src);
    k_fused<<<(N_NODES + 63) / 64, 256, 0, stream>>>(x, sorted_src, start, Wt, WtS,
                                                     b_self, gamma, beta, out);
}

// Round 5
// 395.038 us; speedup vs baseline: 1.2711x; 1.2711x over previous
//
#include <hip/hip_runtime.h>
#include <hip/hip_bf16.h>

#define N_NODES 100000
#define D 256
#define R_REL 8
#define E_EDGES 40000
#define LN_EPS 1e-5f
#define ETOT (R_REL * E_EDGES)                    // 320000
#define SCAN_CH 1024
#define SCAN_NB ((N_NODES + SCAN_CH - 1) / SCAN_CH)  // 98

typedef __attribute__((ext_vector_type(8))) short short8;
typedef __attribute__((ext_vector_type(4))) float f32x4;

__device__ inline ushort bf16u(float f) {
    __hip_bfloat16 h = __float2bfloat16(f);
    return *reinterpret_cast<ushort*>(&h);
}
__device__ inline float bf2f(ushort u) { return __uint_as_float(((unsigned)u) << 16); }

// ---------------------------------------------------------------------------
// BT[o][d] = BigB[d][o] bf16, BigB = [w_self | bases0..3] (256 x 1280).
// grid = 20(ot) x 4(dt) = 80 blocks.
__global__ __launch_bounds__(256) void k_prepB(const float* __restrict__ w_self,
                                               const float* __restrict__ bases,
                                               ushort* __restrict__ BT) {
    __shared__ float tile[64][65];
    int ot = blockIdx.x >> 2, dt = blockIdx.x & 3;
    int o0 = ot * 64, d0 = dt * 64;
    int m = o0 >> 8;                       // 0 = w_self, 1..4 = bases[m-1]
    const float* src = (m == 0) ? w_self : bases + (size_t)(m - 1) * D * D;
    int ol0 = o0 & 255;
    int t = threadIdx.x;
    int cl = t & 63, rw = t >> 6;
    for (int i = 0; i < 16; ++i) {
        int dl = i * 4 + rw;
        tile[dl][cl] = src[(size_t)(d0 + dl) * D + ol0 + cl];
    }
    __syncthreads();
    for (int i = 0; i < 16; ++i) {
        int ol = i * 4 + rw;
        BT[(size_t)(o0 + ol) * D + d0 + cl] = bf16u(tile[cl][ol]);
    }
}

// ---------------------------------------------------------------------------
// CSR over dst (all relations together)
__global__ void k_count(const int* __restrict__ ei, int* __restrict__ cnt) {
    int idx = blockIdx.x * blockDim.x + threadIdx.x;
    if (idx >= ETOT) return;
    int r = idx / E_EDGES, e = idx % E_EDGES;
    int dst = ei[(r * 2 + 1) * E_EDGES + e];
    atomicAdd(&cnt[dst], 1);
}

__global__ __launch_bounds__(256) void k_scanA(const int* __restrict__ cnt,
                                               int* __restrict__ start,
                                               int* __restrict__ sumsA) {
    __shared__ int sc[256];
    int t = threadIdx.x;
    int base = blockIdx.x * SCAN_CH + t * 4;
    int v0 = (base + 0 < N_NODES) ? cnt[base + 0] : 0;
    int v1 = (base + 1 < N_NODES) ? cnt[base + 1] : 0;
    int v2 = (base + 2 < N_NODES) ? cnt[base + 2] : 0;
    int v3 = (base + 3 < N_NODES) ? cnt[base + 3] : 0;
    int ts = v0 + v1 + v2 + v3;
    sc[t] = ts;
    __syncthreads();
    for (int off = 1; off < 256; off <<= 1) {
        int val = (t >= off) ? sc[t - off] : 0;
        __syncthreads();
        sc[t] += val;
        __syncthreads();
    }
    int excl = sc[t] - ts;
    if (base + 0 < N_NODES) start[base + 0] = excl;
    if (base + 1 < N_NODES) start[base + 1] = excl + v0;
    if (base + 2 < N_NODES) start[base + 2] = excl + v0 + v1;
    if (base + 3 < N_NODES) start[base + 3] = excl + v0 + v1 + v2;
    if (t == 255) sumsA[blockIdx.x] = sc[255];
}

__global__ __launch_bounds__(256) void k_scanB(const int* __restrict__ sumsA,
                                               int* __restrict__ sumsB) {
    __shared__ int sc[256];
    int t = threadIdx.x;
    int i0 = t * 4;
    int v0 = (i0 + 0 < SCAN_NB) ? sumsA[i0 + 0] : 0;
    int v1 = (i0 + 1 < SCAN_NB) ? sumsA[i0 + 1] : 0;
    int v2 = (i0 + 2 < SCAN_NB) ? sumsA[i0 + 2] : 0;
    int v3 = (i0 + 3 < SCAN_NB) ? sumsA[i0 + 3] : 0;
    int ts = v0 + v1 + v2 + v3;
    sc[t] = ts;
    __syncthreads();
    for (int off = 1; off < 256; off <<= 1) {
        int val = (t >= off) ? sc[t - off] : 0;
        __syncthreads();
        sc[t] += val;
        __syncthreads();
    }
    int excl = sc[t] - ts;
    if (i0 + 0 < SCAN_NB) sumsB[i0 + 0] = excl;
    if (i0 + 1 < SCAN_NB) sumsB[i0 + 1] = excl + v0;
    if (i0 + 2 < SCAN_NB) sumsB[i0 + 2] = excl + v0 + v1;
    if (i0 + 3 < SCAN_NB) sumsB[i0 + 3] = excl + v0 + v1 + v2;
}

__global__ __launch_bounds__(256) void k_scanC(int* __restrict__ start,
                                               const int* __restrict__ sumsB,
                                               int* __restrict__ cursor) {
    int idx = blockIdx.x * blockDim.x + threadIdx.x;
    if (idx < N_NODES) {
        int v = start[idx] + sumsB[idx / SCAN_CH];
        start[idx] = v;
        cursor[idx] = v;
    }
    if (idx == 0) start[N_NODES] = ETOT;
}

// payload = (r<<20) | src, slotted per dst
__global__ void k_scatter(const int* __restrict__ ei, int* __restrict__ cursor,
                          int* __restrict__ payload) {
    int idx = blockIdx.x * blockDim.x + threadIdx.x;
    if (idx >= ETOT) return;
    int r = idx / E_EDGES, e = idx % E_EDGES;
    int src = ei[r * 2 * E_EDGES + e];
    int dst = ei[(r * 2 + 1) * E_EDGES + e];
    int pos = atomicAdd(&cursor[dst], 1);
    payload[pos] = (r << 20) | src;
}

// ---------------------------------------------------------------------------
// [h | U] = X @ BT^T.  128x128 tile, BK=64, dbuf LDS, XOR-swizzled.
// by 0..1 -> h (f32, into d_out); by 2..9 -> U (bf16).
__global__ __launch_bounds__(256, 2) void k_gemm(const float* __restrict__ x,
                                                 const ushort* __restrict__ BT,
                                                 float* __restrict__ h,
                                                 ushort* __restrict__ U) {
    __shared__ ushort As[2][128 * 64];
    __shared__ ushort Bs[2][128 * 64];
    int t = threadIdx.x;
    int row0 = blockIdx.x * 128;
    int by = blockIdx.y;
    int col0 = by * 128;

    int l = t & 63, w = t >> 6;
    int wr = w >> 1, wc = w & 1;
    int lr = l & 15, lg = l >> 4;

    // --- staging helpers ---
    // B: async global_load_lds, linear dest, inverse-swizzled source (T21)
    auto stageB = [&](int buf, int kt) {
#pragma unroll
        for (int p = 0; p < 4; ++p) {
            int o = p * 4096 + t * 16;                    // linear dest byte
            int rowB = o >> 7;
            int colb = (o & 127) ^ ((rowB & 7) << 4);     // swizzled src col
            const char* gp = (const char*)BT +
                ((size_t)(col0 + rowB) * D + kt * 64) * 2 + colb;
            char* lp = (char*)&Bs[buf][0] + p * 4096 + (t >> 6) * 1024; // wave-uniform
            __builtin_amdgcn_global_load_lds(
                (const __attribute__((address_space(1))) void*)gp,
                (__attribute__((address_space(3))) void*)lp, 16, 0, 0);
        }
    };
    // A: reg-staged f32 -> bf16 -> swizzled ds_write
    auto stageA = [&](int buf, int kt) {
#pragma unroll
        for (int i = 0; i < 4; ++i) {
            int cid = i * 256 + t;                        // 1024 chunks of 8 elems
            int rowA = cid >> 3;
            int kc8 = cid & 7;
            int srcrow = min(row0 + rowA, N_NODES - 1);
            const float4* xp = (const float4*)(x + (size_t)srcrow * D + kt * 64 + kc8 * 8);
            float4 f0 = xp[0], f1 = xp[1];
            short8 v;
            v[0] = (short)bf16u(f0.x); v[1] = (short)bf16u(f0.y);
            v[2] = (short)bf16u(f0.z); v[3] = (short)bf16u(f0.w);
            v[4] = (short)bf16u(f1.x); v[5] = (short)bf16u(f1.y);
            v[6] = (short)bf16u(f1.z); v[7] = (short)bf16u(f1.w);
            int bo = rowA * 128 + ((kc8 * 16) ^ ((rowA & 7) << 4));
            *(short8*)((char*)&As[buf][0] + bo) = v;
        }
    };

    f32x4 acc[4][4] = {};
    stageB(0, 0);
    stageA(0, 0);
    int buf = 0;
    for (int kt = 0; kt < 4; ++kt) {
        __syncthreads();                       // current buf ready
        if (kt < 3) { stageB(buf ^ 1, kt + 1); stageA(buf ^ 1, kt + 1); }
#pragma unroll
        for (int kk = 0; kk < 2; ++kk) {
            int kb = kk * 64 + lg * 16;
            short8 a[4], b[4];
#pragma unroll
            for (int mi = 0; mi < 4; ++mi) {
                int row = wr * 64 + mi * 16 + lr;
                a[mi] = *(const short8*)((const char*)&As[buf][0] +
                         row * 128 + (kb ^ ((row & 7) << 4)));
            }
#pragma unroll
            for (int ni = 0; ni < 4; ++ni) {
                int row = wc * 64 + ni * 16 + lr;
                b[ni] = *(const short8*)((const char*)&Bs[buf][0] +
                         row * 128 + (kb ^ ((row & 7) << 4)));
            }
#pragma unroll
            for (int mi = 0; mi < 4; ++mi)
#pragma unroll
                for (int ni = 0; ni < 4; ++ni)
                    acc[mi][ni] = __builtin_amdgcn_mfma_f32_16x16x32_bf16(
                        a[mi], b[ni], acc[mi][ni], 0, 0, 0);
        }
        buf ^= 1;
    }

    // --- epilogue ---
    if (by < 2) {
#pragma unroll
        for (int mi = 0; mi < 4; ++mi)
#pragma unroll
            for (int j = 0; j < 4; ++j) {
                int row = row0 + wr * 64 + mi * 16 + lg * 4 + j;
                if (row < N_NODES) {
                    float* op = h + (size_t)row * D + col0 + wc * 64 + lr;
#pragma unroll
                    for (int ni = 0; ni < 4; ++ni) op[ni * 16] = acc[mi][ni][j];
                }
            }
    } else {
        int b = (by - 2) >> 1;
        int cbase = ((by - 2) & 1) * 128 + wc * 64 + lr;
#pragma unroll
        for (int mi = 0; mi < 4; ++mi)
#pragma unroll
            for (int j = 0; j < 4; ++j) {
                int row = row0 + wr * 64 + mi * 16 + lg * 4 + j;
                if (row < N_NODES) {
                    ushort* up = U + ((size_t)row * 4 + b) * D + cbase;
#pragma unroll
                    for (int ni = 0; ni < 4; ++ni) up[ni * 16] = bf16u(acc[mi][ni][j]);
                }
            }
    }
}

// ---------------------------------------------------------------------------
// Per dst node (one wave each): msg = sum_e invdeg_{r,dst} sum_b coeff[r,b] U_b[src]
// then out = LN(SiLU(h + bias + msg)).
__global__ __launch_bounds__(256) void k_final(float* __restrict__ out,
                                               const ushort* __restrict__ U,
                                               const int* __restrict__ start,
                                               const int* __restrict__ payload,
                                               const float* __restrict__ coeff,
                                               const float* __restrict__ bias,
                                               const float* __restrict__ gamma,
                                               const float* __restrict__ beta) {
    __shared__ float cf[32];
    int t = threadIdx.x;
    if (t < 32) cf[t] = coeff[t];
    __syncthreads();
    int lane = t & 63, w = t >> 6;
    int n = blockIdx.x * 4 + w;
    int s = start[n], e = start[n + 1];

    // per-relation degree counts packed 8x8 bits
    unsigned long long cnt64 = 0;
    for (int p = s; p < e; ++p) {
        int pk = payload[p];
        cnt64 += 1ull << ((pk >> 20) * 8);
    }
    float msg[4] = {0.f, 0.f, 0.f, 0.f};
    for (int p = s; p < e; ++p) {
        int pk = payload[p];
        int r = pk >> 20, src = pk & 0xFFFFF;
        float inv = 1.0f / (float)((cnt64 >> (r * 8)) & 255);
        const ushort* up = U + (size_t)src * 1024 + lane * 4;
#pragma unroll
        for (int b = 0; b < 4; ++b) {
            float wb = inv * cf[r * 4 + b];
            ushort4 uv = *(const ushort4*)(up + b * 256);
            msg[0] += wb * bf2f(uv.x);
            msg[1] += wb * bf2f(uv.y);
            msg[2] += wb * bf2f(uv.z);
            msg[3] += wb * bf2f(uv.w);
        }
    }

    size_t ro = (size_t)n * D + lane * 4;
    float4 hv = *(const float4*)&out[ro];
    float4 bv = *(const float4*)&bias[lane * 4];
    float a[4];
    a[0] = hv.x + bv.x + msg[0];
    a[1] = hv.y + bv.y + msg[1];
    a[2] = hv.z + bv.z + msg[2];
    a[3] = hv.w + bv.w + msg[3];
    float sum = 0.f, sq = 0.f;
#pragma unroll
    for (int j = 0; j < 4; ++j) {
        a[j] = a[j] / (1.f + expf(-a[j]));
        sum += a[j]; sq += a[j] * a[j];
    }
#pragma unroll
    for (int off = 32; off >= 1; off >>= 1) {
        sum += __shfl_xor(sum, off, 64);
        sq  += __shfl_xor(sq,  off, 64);
    }
    float mean = sum * (1.0f / 256.0f);
    float var = sq * (1.0f / 256.0f) - mean * mean;
    float rs = rsqrtf(var + LN_EPS);
    float4 g4 = *(const float4*)&gamma[lane * 4];
    float4 b4 = *(const float4*)&beta[lane * 4];
    float4 o4;
    o4.x = (a[0] - mean) * rs * g4.x + b4.x;
    o4.y = (a[1] - mean) * rs * g4.y + b4.y;
    o4.z = (a[2] - mean) * rs * g4.z + b4.z;
    o4.w = (a[3] - mean) * rs * g4.w + b4.w;
    *(float4*)&out[ro] = o4;
}

// ---------------------------------------------------------------------------
extern "C" void kernel_launch(void* const* d_in, const int* in_sizes, int n_in,
                              void* d_out, int out_size, void* d_ws, size_t ws_size,
                              hipStream_t stream) {
    const float* x      = (const float*)d_in[0];
    const int*   ei     = (const int*)d_in[1];
    const float* bases  = (const float*)d_in[2];
    const float* coeff  = (const float*)d_in[3];
    const float* w_self = (const float*)d_in[4];
    const float* b_self = (const float*)d_in[5];
    const float* gamma  = (const float*)d_in[6];
    const float* beta   = (const float*)d_in[7];
    float* out = (float*)d_out;

    ushort* BT  = (ushort*)d_ws;                          // 1280*256 bf16 (0.66 MB)
    ushort* U   = BT + (size_t)1280 * D;                  // N*4*256 bf16 (204.8 MB)
    int* cnt    = (int*)(U + (size_t)N_NODES * 4 * D);    // N
    int* start  = cnt + N_NODES;                          // N+1
    int* cursor = start + N_NODES + 1;                    // N
    int* sumsA  = cursor + N_NODES;                       // 98 (pad 128)
    int* sumsB  = sumsA + 128;                            // 98 (pad 128)
    int* payload = sumsB + 128;                           // ETOT

    hipMemsetAsync(cnt, 0, (size_t)N_NODES * sizeof(int), stream);

    k_prepB<<<80, 256, 0, stream>>>(w_self, bases, BT);
    k_count<<<(ETOT + 255) / 256, 256, 0, stream>>>(ei, cnt);
    k_scanA<<<SCAN_NB, 256, 0, stream>>>(cnt, start, sumsA);
    k_scanB<<<1, 256, 0, stream>>>(sumsA, sumsB);
    k_scanC<<<(N_NODES + 255) / 256, 256, 0, stream>>>(start, sumsB, cursor);
    k_scatter<<<(ETOT + 255) / 256, 256, 0, stream>>>(ei, cursor, payload);
    k_gemm<<<dim3((N_NODES + 127) / 128, 10), 256, 0, stream>>>(x, BT, out, U);
    k_final<<<N_NODES / 4, 256, 0, stream>>>(out, U, start, payload, coeff,
                                             b_self, gamma, beta);
}

// Round 6
// 340.793 us; speedup vs baseline: 1.4734x; 1.1592x over previous
//
#include <hip/hip_runtime.h>
#include <hip/hip_bf16.h>

#define N_NODES 100000
#define D 256
#define R_REL 8
#define E_EDGES 40000
#define LN_EPS 1e-5f
#define ETOT (R_REL * E_EDGES)                    // 320000
#define SCAN_CH 1024
#define SCAN_NB ((N_NODES + SCAN_CH - 1) / SCAN_CH)  // 98

typedef __attribute__((ext_vector_type(8))) short short8;
typedef __attribute__((ext_vector_type(4))) float f32x4;

__device__ inline ushort bf16u(float f) {
    __hip_bfloat16 h = __float2bfloat16(f);
    return *reinterpret_cast<ushort*>(&h);
}
__device__ inline float bf2f(ushort u) { return __uint_as_float(((unsigned)u) << 16); }

// ---------------------------------------------------------------------------
// BT[o][d] = BigB[d][o] bf16, BigB = [w_self | bases0..3] (256 x 1280).
__global__ __launch_bounds__(256) void k_prepB(const float* __restrict__ w_self,
                                               const float* __restrict__ bases,
                                               ushort* __restrict__ BT) {
    __shared__ float tile[64][65];
    int ot = blockIdx.x >> 2, dt = blockIdx.x & 3;
    int o0 = ot * 64, d0 = dt * 64;
    int m = o0 >> 8;                       // 0 = w_self, 1..4 = bases[m-1]
    const float* src = (m == 0) ? w_self : bases + (size_t)(m - 1) * D * D;
    int ol0 = o0 & 255;
    int t = threadIdx.x;
    int cl = t & 63, rw = t >> 6;
    for (int i = 0; i < 16; ++i) {
        int dl = i * 4 + rw;
        tile[dl][cl] = src[(size_t)(d0 + dl) * D + ol0 + cl];
    }
    __syncthreads();
    for (int i = 0; i < 16; ++i) {
        int ol = i * 4 + rw;
        BT[(size_t)(o0 + ol) * D + d0 + cl] = bf16u(tile[cl][ol]);
    }
}

// ---------------------------------------------------------------------------
// CSR over dst (all relations together)
__global__ void k_count(const int* __restrict__ ei, int* __restrict__ cnt) {
    int idx = blockIdx.x * blockDim.x + threadIdx.x;
    if (idx >= ETOT) return;
    int r = idx / E_EDGES, e = idx % E_EDGES;
    int dst = ei[(r * 2 + 1) * E_EDGES + e];
    atomicAdd(&cnt[dst], 1);
}

__global__ __launch_bounds__(256) void k_scanA(const int* __restrict__ cnt,
                                               int* __restrict__ start,
                                               int* __restrict__ sumsA) {
    __shared__ int sc[256];
    int t = threadIdx.x;
    int base = blockIdx.x * SCAN_CH + t * 4;
    int v0 = (base + 0 < N_NODES) ? cnt[base + 0] : 0;
    int v1 = (base + 1 < N_NODES) ? cnt[base + 1] : 0;
    int v2 = (base + 2 < N_NODES) ? cnt[base + 2] : 0;
    int v3 = (base + 3 < N_NODES) ? cnt[base + 3] : 0;
    int ts = v0 + v1 + v2 + v3;
    sc[t] = ts;
    __syncthreads();
    for (int off = 1; off < 256; off <<= 1) {
        int val = (t >= off) ? sc[t - off] : 0;
        __syncthreads();
        sc[t] += val;
        __syncthreads();
    }
    int excl = sc[t] - ts;
    if (base + 0 < N_NODES) start[base + 0] = excl;
    if (base + 1 < N_NODES) start[base + 1] = excl + v0;
    if (base + 2 < N_NODES) start[base + 2] = excl + v0 + v1;
    if (base + 3 < N_NODES) start[base + 3] = excl + v0 + v1 + v2;
    if (t == 255) sumsA[blockIdx.x] = sc[255];
}

__global__ __launch_bounds__(256) void k_scanB(const int* __restrict__ sumsA,
                                               int* __restrict__ sumsB) {
    __shared__ int sc[256];
    int t = threadIdx.x;
    int i0 = t * 4;
    int v0 = (i0 + 0 < SCAN_NB) ? sumsA[i0 + 0] : 0;
    int v1 = (i0 + 1 < SCAN_NB) ? sumsA[i0 + 1] : 0;
    int v2 = (i0 + 2 < SCAN_NB) ? sumsA[i0 + 2] : 0;
    int v3 = (i0 + 3 < SCAN_NB) ? sumsA[i0 + 3] : 0;
    int ts = v0 + v1 + v2 + v3;
    sc[t] = ts;
    __syncthreads();
    for (int off = 1; off < 256; off <<= 1) {
        int val = (t >= off) ? sc[t - off] : 0;
        __syncthreads();
        sc[t] += val;
        __syncthreads();
    }
    int excl = sc[t] - ts;
    if (i0 + 0 < SCAN_NB) sumsB[i0 + 0] = excl;
    if (i0 + 1 < SCAN_NB) sumsB[i0 + 1] = excl + v0;
    if (i0 + 2 < SCAN_NB) sumsB[i0 + 2] = excl + v0 + v1;
    if (i0 + 3 < SCAN_NB) sumsB[i0 + 3] = excl + v0 + v1 + v2;
}

__global__ __launch_bounds__(256) void k_scanC(int* __restrict__ start,
                                               const int* __restrict__ sumsB,
                                               int* __restrict__ cursor) {
    int idx = blockIdx.x * blockDim.x + threadIdx.x;
    if (idx < N_NODES) {
        int v = start[idx] + sumsB[idx / SCAN_CH];
        start[idx] = v;
        cursor[idx] = v;
    }
    if (idx == 0) start[N_NODES] = ETOT;
}

// payload = (r<<20) | src, slotted per dst
__global__ void k_scatter(const int* __restrict__ ei, int* __restrict__ cursor,
                          int* __restrict__ payload) {
    int idx = blockIdx.x * blockDim.x + threadIdx.x;
    if (idx >= ETOT) return;
    int r = idx / E_EDGES, e = idx % E_EDGES;
    int src = ei[r * 2 * E_EDGES + e];
    int dst = ei[(r * 2 + 1) * E_EDGES + e];
    int pos = atomicAdd(&cursor[dst], 1);
    payload[pos] = (r << 20) | src;
}

// ---------------------------------------------------------------------------
// [h | U] = X @ BT^T.  Per block: 128 rows x ALL 1280 cols (x fetched once).
// A: 128x256 bf16 LDS (64 KB), staged once, XOR-swizzled.
// B: 5 col-passes of 256x64 bf16, double-buffered (2x32 KB), global_load_lds.
// 512 threads = 8 waves (2 row x 4 col).
__global__ __launch_bounds__(512) void k_gemm(const float* __restrict__ x,
                                              const ushort* __restrict__ BT,
                                              float* __restrict__ h,
                                              ushort* __restrict__ U) {
    __shared__ ushort As[128 * 256];       // 64 KB
    __shared__ ushort Bs[2][256 * 64];     // 2 x 32 KB
    int t = threadIdx.x;
    int row0 = blockIdx.x * 128;
    int l = t & 63, w = t >> 6;
    int wr = w >> 2, wc = w & 3;           // 2 x 4 wave grid
    int lr = l & 15, lg = l >> 4;

    // ---- stage A once: 4096 16B-chunks, swizzled ds_write
#pragma unroll
    for (int i = 0; i < 8; ++i) {
        int cid = i * 512 + t;
        int rowA = cid >> 5;               // 32 chunks per 512B row
        int kc = cid & 31;
        int srcrow = min(row0 + rowA, N_NODES - 1);
        const float4* xp = (const float4*)(x + (size_t)srcrow * D + kc * 8);
        float4 f0 = xp[0], f1 = xp[1];
        short8 v;
        v[0] = (short)bf16u(f0.x); v[1] = (short)bf16u(f0.y);
        v[2] = (short)bf16u(f0.z); v[3] = (short)bf16u(f0.w);
        v[4] = (short)bf16u(f1.x); v[5] = (short)bf16u(f1.y);
        v[6] = (short)bf16u(f1.z); v[7] = (short)bf16u(f1.w);
        int bo = rowA * 512 + ((kc * 16) ^ ((rowA & 7) << 4));
        *(short8*)((char*)As + bo) = v;
    }

    // ---- B staging: linear LDS dest, inverse-swizzled global source (T21)
    auto stageB = [&](int buf, int pass, int kt) {
#pragma unroll
        for (int p = 0; p < 4; ++p) {
            int o = p * 8192 + t * 16;                  // linear byte in 32KB tile
            int rowB = o >> 7;                          // 128B per B-row
            int colb = (o & 127) ^ ((rowB & 7) << 4);   // swizzled source byte
            const char* gp = (const char*)BT +
                ((size_t)(pass * 256 + rowB) * D + kt * 64) * 2 + colb;
            char* lp = (char*)&Bs[buf][0] + p * 8192 + (t >> 6) * 1024;  // wave-uniform
            __builtin_amdgcn_global_load_lds(
                (const __attribute__((address_space(1))) void*)gp,
                (__attribute__((address_space(3))) void*)lp, 16, 0, 0);
        }
    };

    for (int pass = 0; pass < 5; ++pass) {
        stageB(0, pass, 0);
        f32x4 acc[4][4] = {};
        int buf = 0;
        for (int kt = 0; kt < 4; ++kt) {
            __syncthreads();               // buf ready; prior reads of buf^1 done
            if (kt < 3) stageB(buf ^ 1, pass, kt + 1);
#pragma unroll
            for (int kk = 0; kk < 2; ++kk) {
                int kb = kt * 128 + kk * 64 + lg * 16;   // A byte col
                int kb2 = kk * 64 + lg * 16;             // B byte col
                short8 a[4], b[4];
#pragma unroll
                for (int mi = 0; mi < 4; ++mi) {
                    int row = wr * 64 + mi * 16 + lr;
                    a[mi] = *(const short8*)((const char*)As +
                             row * 512 + (kb ^ ((row & 7) << 4)));
                }
#pragma unroll
                for (int ni = 0; ni < 4; ++ni) {
                    int rb = wc * 64 + ni * 16 + lr;
                    b[ni] = *(const short8*)((const char*)&Bs[buf][0] +
                             rb * 128 + (kb2 ^ ((rb & 7) << 4)));
                }
#pragma unroll
                for (int mi = 0; mi < 4; ++mi)
#pragma unroll
                    for (int ni = 0; ni < 4; ++ni)
                        acc[mi][ni] = __builtin_amdgcn_mfma_f32_16x16x32_bf16(
                            a[mi], b[ni], acc[mi][ni], 0, 0, 0);
            }
            buf ^= 1;
        }
        // ---- epilogue for this col-pass (regs only, no LDS)
        if (pass == 0) {
#pragma unroll
            for (int mi = 0; mi < 4; ++mi)
#pragma unroll
                for (int j = 0; j < 4; ++j) {
                    int row = row0 + wr * 64 + mi * 16 + lg * 4 + j;
                    if (row < N_NODES) {
                        float* op = h + (size_t)row * D + wc * 64 + lr;
#pragma unroll
                        for (int ni = 0; ni < 4; ++ni) op[ni * 16] = acc[mi][ni][j];
                    }
                }
        } else {
            int b = pass - 1;
#pragma unroll
            for (int mi = 0; mi < 4; ++mi)
#pragma unroll
                for (int j = 0; j < 4; ++j) {
                    int row = row0 + wr * 64 + mi * 16 + lg * 4 + j;
                    if (row < N_NODES) {
                        ushort* up = U + ((size_t)row * 4 + b) * D + wc * 64 + lr;
#pragma unroll
                        for (int ni = 0; ni < 4; ++ni) up[ni * 16] = bf16u(acc[mi][ni][j]);
                    }
                }
        }
    }
}

// ---------------------------------------------------------------------------
// Per dst node (one wave each): msg = sum_e invdeg_{r,dst} sum_b coeff[r,b] U_b[src]
// then out = LN(SiLU(h + bias + msg)).
__global__ __launch_bounds__(256) void k_final(float* __restrict__ out,
                                               const ushort* __restrict__ U,
                                               const int* __restrict__ start,
                                               const int* __restrict__ payload,
                                               const float* __restrict__ coeff,
                                               const float* __restrict__ bias,
                                               const float* __restrict__ gamma,
                                               const float* __restrict__ beta) {
    __shared__ float cf[32];
    int t = threadIdx.x;
    if (t < 32) cf[t] = coeff[t];
    __syncthreads();
    int lane = t & 63, w = t >> 6;
    int n = blockIdx.x * 4 + w;
    int s = start[n], e = start[n + 1];

    unsigned long long cnt64 = 0;
    for (int p = s; p < e; ++p) {
        int pk = payload[p];
        cnt64 += 1ull << ((pk >> 20) * 8);
    }
    float msg[4] = {0.f, 0.f, 0.f, 0.f};
    for (int p = s; p < e; ++p) {
        int pk = payload[p];
        int r = pk >> 20, src = pk & 0xFFFFF;
        float inv = 1.0f / (float)((cnt64 >> (r * 8)) & 255);
        const ushort* up = U + (size_t)src * 1024 + lane * 4;
#pragma unroll
        for (int b = 0; b < 4; ++b) {
            float wb = inv * cf[r * 4 + b];
            ushort4 uv = *(const ushort4*)(up + b * 256);
            msg[0] += wb * bf2f(uv.x);
            msg[1] += wb * bf2f(uv.y);
            msg[2] += wb * bf2f(uv.z);
            msg[3] += wb * bf2f(uv.w);
        }
    }

    size_t ro = (size_t)n * D + lane * 4;
    float4 hv = *(const float4*)&out[ro];
    float4 bv = *(const float4*)&bias[lane * 4];
    float a[4];
    a[0] = hv.x + bv.x + msg[0];
    a[1] = hv.y + bv.y + msg[1];
    a[2] = hv.z + bv.z + msg[2];
    a[3] = hv.w + bv.w + msg[3];
    float sum = 0.f, sq = 0.f;
#pragma unroll
    for (int j = 0; j < 4; ++j) {
        a[j] = a[j] / (1.f + expf(-a[j]));
        sum += a[j]; sq += a[j] * a[j];
    }
#pragma unroll
    for (int off = 32; off >= 1; off >>= 1) {
        sum += __shfl_xor(sum, off, 64);
        sq  += __shfl_xor(sq,  off, 64);
    }
    float mean = sum * (1.0f / 256.0f);
    float var = sq * (1.0f / 256.0f) - mean * mean;
    float rs = rsqrtf(var + LN_EPS);
    float4 g4 = *(const float4*)&gamma[lane * 4];
    float4 b4 = *(const float4*)&beta[lane * 4];
    float4 o4;
    o4.x = (a[0] - mean) * rs * g4.x + b4.x;
    o4.y = (a[1] - mean) * rs * g4.y + b4.y;
    o4.z = (a[2] - mean) * rs * g4.z + b4.z;
    o4.w = (a[3] - mean) * rs * g4.w + b4.w;
    *(float4*)&out[ro] = o4;
}

// ---------------------------------------------------------------------------
extern "C" void kernel_launch(void* const* d_in, const int* in_sizes, int n_in,
                              void* d_out, int out_size, void* d_ws, size_t ws_size,
                              hipStream_t stream) {
    const float* x      = (const float*)d_in[0];
    const int*   ei     = (const int*)d_in[1];
    const float* bases  = (const float*)d_in[2];
    const float* coeff  = (const float*)d_in[3];
    const float* w_self = (const float*)d_in[4];
    const float* b_self = (const float*)d_in[5];
    const float* gamma  = (const float*)d_in[6];
    const float* beta   = (const float*)d_in[7];
    float* out = (float*)d_out;

    ushort* BT  = (ushort*)d_ws;                          // 1280*256 bf16 (0.66 MB)
    ushort* U   = BT + (size_t)1280 * D;                  // N*4*256 bf16 (204.8 MB)
    int* cnt    = (int*)(U + (size_t)N_NODES * 4 * D);    // N
    int* start  = cnt + N_NODES;                          // N+1
    int* cursor = start + N_NODES + 1;                    // N
    int* sumsA  = cursor + N_NODES;                       // 98 (pad 128)
    int* sumsB  = sumsA + 128;                            // 98 (pad 128)
    int* payload = sumsB + 128;                           // ETOT

    hipMemsetAsync(cnt, 0, (size_t)N_NODES * sizeof(int), stream);

    k_prepB<<<80, 256, 0, stream>>>(w_self, bases, BT);
    k_count<<<(ETOT + 255) / 256, 256, 0, stream>>>(ei, cnt);
    k_scanA<<<SCAN_NB, 256, 0, stream>>>(cnt, start, sumsA);
    k_scanB<<<1, 256, 0, stream>>>(sumsA, sumsB);
    k_scanC<<<(N_NODES + 255) / 256, 256, 0, stream>>>(start, sumsB, cursor);
    k_scatter<<<(ETOT + 255) / 256, 256, 0, stream>>>(ei, cursor, payload);
    k_gemm<<<(N_NODES + 127) / 128, 512, 0, stream>>>(x, BT, out, U);
    k_final<<<N_NODES / 4, 256, 0, stream>>>(out, U, start, payload, coeff,
                                             b_self, gamma, beta);
}

// Round 7
// 290.011 us; speedup vs baseline: 1.7314x; 1.1751x over previous
//
#include <hip/hip_runtime.h>
#include <hip/hip_bf16.h>

#define N_NODES 100000
#define D 256
#define R_REL 8
#define E_EDGES 40000
#define LN_EPS 1e-5f
#define ETOT (R_REL * E_EDGES)                    // 320000
#define SCAN_CH 1024
#define SCAN_NB ((N_NODES + SCAN_CH - 1) / SCAN_CH)  // 98

typedef __attribute__((ext_vector_type(8))) short short8;
typedef __attribute__((ext_vector_type(4))) float f32x4;
typedef unsigned char uchar;

__device__ inline ushort bf16u(float f) {
    __hip_bfloat16 h = __float2bfloat16(f);
    return *reinterpret_cast<ushort*>(&h);
}

// ---------------------------------------------------------------------------
// BT[o][d] = BigB[d][o] bf16, BigB = [w_self | bases0..3] (256 x 1280).
__global__ __launch_bounds__(256) void k_prepB(const float* __restrict__ w_self,
                                               const float* __restrict__ bases,
                                               ushort* __restrict__ BT) {
    __shared__ float tile[64][65];
    int ot = blockIdx.x >> 2, dt = blockIdx.x & 3;
    int o0 = ot * 64, d0 = dt * 64;
    int m = o0 >> 8;                       // 0 = w_self, 1..4 = bases[m-1]
    const float* src = (m == 0) ? w_self : bases + (size_t)(m - 1) * D * D;
    int ol0 = o0 & 255;
    int t = threadIdx.x;
    int cl = t & 63, rw = t >> 6;
    for (int i = 0; i < 16; ++i) {
        int dl = i * 4 + rw;
        tile[dl][cl] = src[(size_t)(d0 + dl) * D + ol0 + cl];
    }
    __syncthreads();
    for (int i = 0; i < 16; ++i) {
        int ol = i * 4 + rw;
        BT[(size_t)(o0 + ol) * D + d0 + cl] = bf16u(tile[cl][ol]);
    }
}

// ---------------------------------------------------------------------------
// CSR over dst (all relations together)
__global__ void k_count(const int* __restrict__ ei, int* __restrict__ cnt) {
    int idx = blockIdx.x * blockDim.x + threadIdx.x;
    if (idx >= ETOT) return;
    int r = idx / E_EDGES, e = idx % E_EDGES;
    int dst = ei[(r * 2 + 1) * E_EDGES + e];
    atomicAdd(&cnt[dst], 1);
}

__global__ __launch_bounds__(256) void k_scanA(const int* __restrict__ cnt,
                                               int* __restrict__ start,
                                               int* __restrict__ sumsA) {
    __shared__ int sc[256];
    int t = threadIdx.x;
    int base = blockIdx.x * SCAN_CH + t * 4;
    int v0 = (base + 0 < N_NODES) ? cnt[base + 0] : 0;
    int v1 = (base + 1 < N_NODES) ? cnt[base + 1] : 0;
    int v2 = (base + 2 < N_NODES) ? cnt[base + 2] : 0;
    int v3 = (base + 3 < N_NODES) ? cnt[base + 3] : 0;
    int ts = v0 + v1 + v2 + v3;
    sc[t] = ts;
    __syncthreads();
    for (int off = 1; off < 256; off <<= 1) {
        int val = (t >= off) ? sc[t - off] : 0;
        __syncthreads();
        sc[t] += val;
        __syncthreads();
    }
    int excl = sc[t] - ts;
    if (base + 0 < N_NODES) start[base + 0] = excl;
    if (base + 1 < N_NODES) start[base + 1] = excl + v0;
    if (base + 2 < N_NODES) start[base + 2] = excl + v0 + v1;
    if (base + 3 < N_NODES) start[base + 3] = excl + v0 + v1 + v2;
    if (t == 255) sumsA[blockIdx.x] = sc[255];
}

__global__ __launch_bounds__(256) void k_scanB(const int* __restrict__ sumsA,
                                               int* __restrict__ sumsB) {
    __shared__ int sc[256];
    int t = threadIdx.x;
    int i0 = t * 4;
    int v0 = (i0 + 0 < SCAN_NB) ? sumsA[i0 + 0] : 0;
    int v1 = (i0 + 1 < SCAN_NB) ? sumsA[i0 + 1] : 0;
    int v2 = (i0 + 2 < SCAN_NB) ? sumsA[i0 + 2] : 0;
    int v3 = (i0 + 3 < SCAN_NB) ? sumsA[i0 + 3] : 0;
    int ts = v0 + v1 + v2 + v3;
    sc[t] = ts;
    __syncthreads();
    for (int off = 1; off < 256; off <<= 1) {
        int val = (t >= off) ? sc[t - off] : 0;
        __syncthreads();
        sc[t] += val;
        __syncthreads();
    }
    int excl = sc[t] - ts;
    if (i0 + 0 < SCAN_NB) sumsB[i0 + 0] = excl;
    if (i0 + 1 < SCAN_NB) sumsB[i0 + 1] = excl + v0;
    if (i0 + 2 < SCAN_NB) sumsB[i0 + 2] = excl + v0 + v1;
    if (i0 + 3 < SCAN_NB) sumsB[i0 + 3] = excl + v0 + v1 + v2;
}

__global__ __launch_bounds__(256) void k_scanC(int* __restrict__ start,
                                               const int* __restrict__ sumsB,
                                               int* __restrict__ cursor) {
    int idx = blockIdx.x * blockDim.x + threadIdx.x;
    if (idx < N_NODES) {
        int v = start[idx] + sumsB[idx / SCAN_CH];
        start[idx] = v;
        cursor[idx] = v;
    }
    if (idx == 0) start[N_NODES] = ETOT;
}

// payload = (r<<20) | src, slotted per dst
__global__ void k_scatter(const int* __restrict__ ei, int* __restrict__ cursor,
                          int* __restrict__ payload) {
    int idx = blockIdx.x * blockDim.x + threadIdx.x;
    if (idx >= ETOT) return;
    int r = idx / E_EDGES, e = idx % E_EDGES;
    int src = ei[r * 2 * E_EDGES + e];
    int dst = ei[(r * 2 + 1) * E_EDGES + e];
    int pos = atomicAdd(&cursor[dst], 1);
    payload[pos] = (r << 20) | src;
}

// ---------------------------------------------------------------------------
// [h | U] = X @ BT^T.  Per block: 128 rows x ALL 1280 cols (x fetched once).
// pass 0 -> h (f32); passes 1..4 -> U plane (fp8 e4m3, value*64).
__global__ __launch_bounds__(512) void k_gemm(const float* __restrict__ x,
                                              const ushort* __restrict__ BT,
                                              float* __restrict__ h,
                                              uchar* __restrict__ U) {
    __shared__ ushort As[128 * 256];       // 64 KB
    __shared__ ushort Bs[2][256 * 64];     // 2 x 32 KB
    int t = threadIdx.x;
    int row0 = blockIdx.x * 128;
    int l = t & 63, w = t >> 6;
    int wr = w >> 2, wc = w & 3;           // 2 x 4 wave grid
    int lr = l & 15, lg = l >> 4;

    // ---- stage A once: 4096 16B-chunks, swizzled ds_write
#pragma unroll
    for (int i = 0; i < 8; ++i) {
        int cid = i * 512 + t;
        int rowA = cid >> 5;               // 32 chunks per 512B row
        int kc = cid & 31;
        int srcrow = min(row0 + rowA, N_NODES - 1);
        const float4* xp = (const float4*)(x + (size_t)srcrow * D + kc * 8);
        float4 f0 = xp[0], f1 = xp[1];
        short8 v;
        v[0] = (short)bf16u(f0.x); v[1] = (short)bf16u(f0.y);
        v[2] = (short)bf16u(f0.z); v[3] = (short)bf16u(f0.w);
        v[4] = (short)bf16u(f1.x); v[5] = (short)bf16u(f1.y);
        v[6] = (short)bf16u(f1.z); v[7] = (short)bf16u(f1.w);
        int bo = rowA * 512 + ((kc * 16) ^ ((rowA & 7) << 4));
        *(short8*)((char*)As + bo) = v;
    }

    // ---- B staging: linear LDS dest, inverse-swizzled global source (T21)
    auto stageB = [&](int buf, int pass, int kt) {
#pragma unroll
        for (int p = 0; p < 4; ++p) {
            int o = p * 8192 + t * 16;                  // linear byte in 32KB tile
            int rowB = o >> 7;                          // 128B per B-row
            int colb = (o & 127) ^ ((rowB & 7) << 4);   // swizzled source byte
            const char* gp = (const char*)BT +
                ((size_t)(pass * 256 + rowB) * D + kt * 64) * 2 + colb;
            char* lp = (char*)&Bs[buf][0] + p * 8192 + (t >> 6) * 1024;  // wave-uniform
            __builtin_amdgcn_global_load_lds(
                (const __attribute__((address_space(1))) void*)gp,
                (__attribute__((address_space(3))) void*)lp, 16, 0, 0);
        }
    };

    for (int pass = 0; pass < 5; ++pass) {
        stageB(0, pass, 0);
        f32x4 acc[4][4] = {};
        int buf = 0;
        for (int kt = 0; kt < 4; ++kt) {
            __syncthreads();               // buf ready; prior reads of buf^1 done
            if (kt < 3) stageB(buf ^ 1, pass, kt + 1);
#pragma unroll
            for (int kk = 0; kk < 2; ++kk) {
                int kb = kt * 128 + kk * 64 + lg * 16;   // A byte col
                int kb2 = kk * 64 + lg * 16;             // B byte col
                short8 a[4], b[4];
#pragma unroll
                for (int mi = 0; mi < 4; ++mi) {
                    int row = wr * 64 + mi * 16 + lr;
                    a[mi] = *(const short8*)((const char*)As +
                             row * 512 + (kb ^ ((row & 7) << 4)));
                }
#pragma unroll
                for (int ni = 0; ni < 4; ++ni) {
                    int rb = wc * 64 + ni * 16 + lr;
                    b[ni] = *(const short8*)((const char*)&Bs[buf][0] +
                             rb * 128 + (kb2 ^ ((rb & 7) << 4)));
                }
#pragma unroll
                for (int mi = 0; mi < 4; ++mi)
#pragma unroll
                    for (int ni = 0; ni < 4; ++ni)
                        acc[mi][ni] = __builtin_amdgcn_mfma_f32_16x16x32_bf16(
                            a[mi], b[ni], acc[mi][ni], 0, 0, 0);
            }
            buf ^= 1;
        }
        // ---- epilogue for this col-pass (regs only, no LDS)
        if (pass == 0) {
#pragma unroll
            for (int mi = 0; mi < 4; ++mi)
#pragma unroll
                for (int j = 0; j < 4; ++j) {
                    int row = row0 + wr * 64 + mi * 16 + lg * 4 + j;
                    if (row < N_NODES) {
                        float* op = h + (size_t)row * D + wc * 64 + lr;
#pragma unroll
                        for (int ni = 0; ni < 4; ++ni) op[ni * 16] = acc[mi][ni][j];
                    }
                }
        } else {
            int b = pass - 1;
#pragma unroll
            for (int mi = 0; mi < 4; ++mi)
#pragma unroll
                for (int j = 0; j < 4; ++j) {
                    int row = row0 + wr * 64 + mi * 16 + lg * 4 + j;
                    if (row < N_NODES) {
                        // U layout: [src][b*256 + col], fp8 e4m3 of value*64
                        uchar* up = U + (size_t)row * 1024 + b * 256 + wc * 64 + lr;
                        unsigned p01 = __builtin_amdgcn_cvt_pk_fp8_f32(
                            acc[mi][0][j] * 64.0f, acc[mi][1][j] * 64.0f, 0, 0);
                        unsigned p23 = __builtin_amdgcn_cvt_pk_fp8_f32(
                            acc[mi][2][j] * 64.0f, acc[mi][3][j] * 64.0f, 0, 0);
                        up[0]  = (uchar)(p01 & 0xFF);
                        up[16] = (uchar)((p01 >> 8) & 0xFF);
                        up[32] = (uchar)(p23 & 0xFF);
                        up[48] = (uchar)((p23 >> 8) & 0xFF);
                    }
                }
        }
    }
}

// ---------------------------------------------------------------------------
// Per dst node (one wave each): msg = sum_e invdeg_{r,dst} sum_b coeff[r,b] U_b[src]
// U is fp8(value*64); lane bq=lane>>4 handles plane bq, cols cb*16..+15 (cb=lane&15).
// Cross-b combine via shfl_xor(16/32); then out = LN(SiLU(h + bias + msg)).
__global__ __launch_bounds__(256) void k_final(float* __restrict__ out,
                                               const uchar* __restrict__ U,
                                               const int* __restrict__ start,
                                               const int* __restrict__ payload,
                                               const float* __restrict__ coeff,
                                               const float* __restrict__ bias,
                                               const float* __restrict__ gamma,
                                               const float* __restrict__ beta) {
    __shared__ float cf[32];
    int t = threadIdx.x;
    if (t < 32) cf[t] = coeff[t];
    __syncthreads();
    int lane = t & 63, w = t >> 6;
    int n = blockIdx.x * 4 + w;
    int s = start[n], e = start[n + 1];
    int bq = lane >> 4;                    // basis plane for this lane
    int cb = lane & 15;                    // col block (16 cols)

    // per-relation degree counts packed 8x8 bits
    unsigned long long cnt64 = 0;
    for (int p = s; p < e; ++p)
        cnt64 += 1ull << ((payload[p] >> 20) * 8);

    float msg[16] = {0.f,0.f,0.f,0.f,0.f,0.f,0.f,0.f,
                     0.f,0.f,0.f,0.f,0.f,0.f,0.f,0.f};
    for (int p = s; p < e; ++p) {
        int pk = payload[p];
        int r = pk >> 20, src = pk & 0xFFFFF;
        float dg = (float)((unsigned)(cnt64 >> (r * 8)) & 255u);
        float wb = cf[r * 4 + bq] * __builtin_amdgcn_rcpf(dg) * 0.015625f;
        uint4 v = *(const uint4*)(U + (size_t)src * 1024 + lane * 16);
        msg[0]  += wb * __builtin_amdgcn_cvt_f32_fp8(v.x, 0);
        msg[1]  += wb * __builtin_amdgcn_cvt_f32_fp8(v.x, 1);
        msg[2]  += wb * __builtin_amdgcn_cvt_f32_fp8(v.x, 2);
        msg[3]  += wb * __builtin_amdgcn_cvt_f32_fp8(v.x, 3);
        msg[4]  += wb * __builtin_amdgcn_cvt_f32_fp8(v.y, 0);
        msg[5]  += wb * __builtin_amdgcn_cvt_f32_fp8(v.y, 1);
        msg[6]  += wb * __builtin_amdgcn_cvt_f32_fp8(v.y, 2);
        msg[7]  += wb * __builtin_amdgcn_cvt_f32_fp8(v.y, 3);
        msg[8]  += wb * __builtin_amdgcn_cvt_f32_fp8(v.z, 0);
        msg[9]  += wb * __builtin_amdgcn_cvt_f32_fp8(v.z, 1);
        msg[10] += wb * __builtin_amdgcn_cvt_f32_fp8(v.z, 2);
        msg[11] += wb * __builtin_amdgcn_cvt_f32_fp8(v.z, 3);
        msg[12] += wb * __builtin_amdgcn_cvt_f32_fp8(v.w, 0);
        msg[13] += wb * __builtin_amdgcn_cvt_f32_fp8(v.w, 1);
        msg[14] += wb * __builtin_amdgcn_cvt_f32_fp8(v.w, 2);
        msg[15] += wb * __builtin_amdgcn_cvt_f32_fp8(v.w, 3);
    }
    // combine the 4 basis planes: lanes lane^16, lane^32 hold same cols
#pragma unroll
    for (int i = 0; i < 16; ++i) {
        msg[i] += __shfl_xor(msg[i], 16, 64);
        msg[i] += __shfl_xor(msg[i], 32, 64);
    }

    // this lane finalizes 4 cols: cb*16 + bq*4 + 0..3
    int col = cb * 16 + bq * 4;
    size_t ro = (size_t)n * D + col;
    float4 hv = *(const float4*)&out[ro];
    float4 bv = *(const float4*)&bias[col];
    float a[4];
    a[0] = hv.x + bv.x + msg[bq * 4 + 0];
    a[1] = hv.y + bv.y + msg[bq * 4 + 1];
    a[2] = hv.z + bv.z + msg[bq * 4 + 2];
    a[3] = hv.w + bv.w + msg[bq * 4 + 3];
    float sum = 0.f, sq = 0.f;
#pragma unroll
    for (int j = 0; j < 4; ++j) {
        a[j] = a[j] / (1.f + expf(-a[j]));
        sum += a[j]; sq += a[j] * a[j];
    }
#pragma unroll
    for (int off = 32; off >= 1; off >>= 1) {
        sum += __shfl_xor(sum, off, 64);
        sq  += __shfl_xor(sq,  off, 64);
    }
    float mean = sum * (1.0f / 256.0f);
    float var = sq * (1.0f / 256.0f) - mean * mean;
    float rs = rsqrtf(var + LN_EPS);
    float4 g4 = *(const float4*)&gamma[col];
    float4 b4 = *(const float4*)&beta[col];
    float4 o4;
    o4.x = (a[0] - mean) * rs * g4.x + b4.x;
    o4.y = (a[1] - mean) * rs * g4.y + b4.y;
    o4.z = (a[2] - mean) * rs * g4.z + b4.z;
    o4.w = (a[3] - mean) * rs * g4.w + b4.w;
    *(float4*)&out[ro] = o4;
}

// ---------------------------------------------------------------------------
extern "C" void kernel_launch(void* const* d_in, const int* in_sizes, int n_in,
                              void* d_out, int out_size, void* d_ws, size_t ws_size,
                              hipStream_t stream) {
    const float* x      = (const float*)d_in[0];
    const int*   ei     = (const int*)d_in[1];
    const float* bases  = (const float*)d_in[2];
    const float* coeff  = (const float*)d_in[3];
    const float* w_self = (const float*)d_in[4];
    const float* b_self = (const float*)d_in[5];
    const float* gamma  = (const float*)d_in[6];
    const float* beta   = (const float*)d_in[7];
    float* out = (float*)d_out;

    ushort* BT  = (ushort*)d_ws;                          // 1280*256 bf16 (0.66 MB)
    uchar*  U   = (uchar*)(BT + (size_t)1280 * D);        // N*1024 fp8 (102.4 MB)
    int* cnt    = (int*)(U + (size_t)N_NODES * 1024);     // N
    int* start  = cnt + N_NODES;                          // N+1
    int* cursor = start + N_NODES + 1;                    // N
    int* sumsA  = cursor + N_NODES;                       // 98 (pad 128)
    int* sumsB  = sumsA + 128;                            // 98 (pad 128)
    int* payload = sumsB + 128;                           // ETOT

    hipMemsetAsync(cnt, 0, (size_t)N_NODES * sizeof(int), stream);

    k_prepB<<<80, 256, 0, stream>>>(w_self, bases, BT);
    k_count<<<(ETOT + 255) / 256, 256, 0, stream>>>(ei, cnt);
    k_scanA<<<SCAN_NB, 256, 0, stream>>>(cnt, start, sumsA);
    k_scanB<<<1, 256, 0, stream>>>(sumsA, sumsB);
    k_scanC<<<(N_NODES + 255) / 256, 256, 0, stream>>>(start, sumsB, cursor);
    k_scatter<<<(ETOT + 255) / 256, 256, 0, stream>>>(ei, cursor, payload);
    k_gemm<<<(N_NODES + 127) / 128, 512, 0, stream>>>(x, BT, out, U);
    k_final<<<N_NODES / 4, 256, 0, stream>>>(out, U, start, payload, coeff,
                                             b_self, gamma, beta);
}